// Round 1
// baseline (241.622 us; speedup 1.0000x reference)
//
#include <hip/hip_runtime.h>

#define B_  2
#define S_  2048
#define D_  1024
#define H_  16
#define HD_ 64
#define MM  (B_ * S_)  // 4096 rows in all projection GEMMs

typedef __bf16 bf16;
typedef __attribute__((ext_vector_type(8))) __bf16 bf16x8;
typedef __attribute__((ext_vector_type(4))) __bf16 bf16x4;
typedef __attribute__((ext_vector_type(4))) float  f32x4;

// exp2 via the native v_exp_f32 (computes 2^x). Avoids glibc __exp2f macro.
__device__ inline float exp2g(float x) { return __builtin_amdgcn_exp2f(x); }

// Load 8 contiguous elements as bf16x8 (converting if fp32).
__device__ inline bf16x8 load8(const bf16* p) { return *(const bf16x8*)p; }
__device__ inline bf16x8 load8(const float* p) {
  float4 a = *(const float4*)p;
  float4 b = *(const float4*)(p + 4);
  bf16x8 r;
  r[0] = (bf16)a.x; r[1] = (bf16)a.y; r[2] = (bf16)a.z; r[3] = (bf16)a.w;
  r[4] = (bf16)b.x; r[5] = (bf16)b.y; r[6] = (bf16)b.z; r[7] = (bf16)b.w;
  return r;
}

// Async global->LDS DMA, 16 B per lane (dest = wave-uniform base + lane*16).
__device__ inline void gld16(void* lds, const void* g) {
  __builtin_amdgcn_global_load_lds(
      (const __attribute__((address_space(1))) unsigned int*)g,
      (__attribute__((address_space(3))) unsigned int*)lds, 16, 0, 0);
}

// ---------------------------------------------------------------------------
// z 0..3: 32x32-tiled weight transpose fp32->bf16.
// z 4..15: bulk fp32->bf16 convert of q_in/k_in/v_in (1M elems per plane).
// ---------------------------------------------------------------------------
__global__ __launch_bounds__(256) void transpose_w(
    const float* __restrict__ W0, const float* __restrict__ W1,
    const float* __restrict__ W2, const float* __restrict__ W3,
    bf16* __restrict__ T0, bf16* __restrict__ T1,
    bf16* __restrict__ T2, bf16* __restrict__ T3,
    const float* __restrict__ X0, const float* __restrict__ X1,
    const float* __restrict__ X2,
    bf16* __restrict__ Y0, bf16* __restrict__ Y1, bf16* __restrict__ Y2) {
  const int z = blockIdx.z;
  if (z >= 4) {  // convert plane
    const int p = z - 4, t = p >> 2;
    const float* src = t == 0 ? X0 : t == 1 ? X1 : X2;
    bf16* dst = t == 0 ? Y0 : t == 1 ? Y1 : Y2;
    long base = ((long)(p & 3) << 20) +
                (long)(blockIdx.y * 32 + blockIdx.x) * 1024 + threadIdx.x * 4;
    float4 v = *(const float4*)&src[base];
    bf16x4 o4;
    o4[0] = (bf16)v.x; o4[1] = (bf16)v.y; o4[2] = (bf16)v.z; o4[3] = (bf16)v.w;
    *(bf16x4*)&dst[base] = o4;
    return;
  }
  __shared__ bf16 t[32][40];
  const float* in = z == 0 ? W0 : z == 1 ? W1 : z == 2 ? W2 : W3;
  bf16* out = z == 0 ? T0 : z == 1 ? T1 : z == 2 ? T2 : T3;
  const int tx = threadIdx.x & 31;
  const int ty = threadIdx.x >> 5;  // 0..7
  const int r0 = blockIdx.y * 32, c0 = blockIdx.x * 32;
#pragma unroll
  for (int j = 0; j < 32; j += 8)
    t[ty + j][tx] = (bf16)in[(long)(r0 + ty + j) * D_ + (c0 + tx)];
  __syncthreads();
#pragma unroll
  for (int j = 0; j < 32; j += 8)
    out[(long)(c0 + ty + j) * D_ + (r0 + tx)] = t[tx][ty + j];
}

// ---------------------------------------------------------------------------
// V [B,S,H,HD] (bf16) -> VT [B,H,HD,S]  (coalesced LDS-bounce transpose)
// ---------------------------------------------------------------------------
__global__ __launch_bounds__(256) void transpose_v64(const bf16* __restrict__ V,
                                                     bf16* __restrict__ VT) {
  __shared__ bf16 t[64][72];
  const int tid = threadIdx.x;
  const int s0 = blockIdx.x * 64;
  const int bh = blockIdx.y;
  const int b = bh >> 4, h = bh & 15;
  const bf16* ip = V + (long)b * S_ * D_ + h * HD_;
  bf16* op = VT + (long)bh * HD_ * S_;
#pragma unroll
  for (int i = 0; i < 2; ++i) {
    int c = tid + i * 256;
    int r = c >> 3, cc = (c & 7) * 8;
    *(bf16x8*)&t[r][cc] = *(const bf16x8*)&ip[(long)(s0 + r) * D_ + cc];
  }
  __syncthreads();
#pragma unroll
  for (int i = 0; i < 2; ++i) {
    int c = tid + i * 256;
    int d = c >> 3, sc = (c & 7) * 8;
    bf16x8 v;
#pragma unroll
    for (int j = 0; j < 8; ++j) v[j] = t[sc + j][d];
    *(bf16x8*)&op[(long)d * S_ + s0 + sc] = v;
  }
}

// ---------------------------------------------------------------------------
// Batched C[M,N] = A[M,K] @ Bt[N,K]^T + bias[N], z selects operand triple.
// BK=64 via two [128][32] half-buffers (keeps 64B-stride conflict-free
// fragment reads and DMA lane-contiguity); halves barrier count vs R12.
// ---------------------------------------------------------------------------
template <typename AT, typename OT>
__global__ __launch_bounds__(256) void gemm_bt_dma(
    const AT* __restrict__ A0, const AT* __restrict__ A1, const AT* __restrict__ A2,
    const bf16* __restrict__ B0, const bf16* __restrict__ B1, const bf16* __restrict__ B2,
    const float* __restrict__ c0, const float* __restrict__ c1, const float* __restrict__ c2,
    OT* __restrict__ C0, OT* __restrict__ C1, OT* __restrict__ C2,
    int M, int N, int K) {
  __shared__ bf16 lA[2][128][32];
  __shared__ bf16 lB[2][128][32];
  const int z = blockIdx.z;
  const AT*    A    = z == 0 ? A0 : z == 1 ? A1 : A2;
  const bf16*  Bt   = z == 0 ? B0 : z == 1 ? B1 : B2;
  const float* bias = z == 0 ? c0 : z == 1 ? c1 : c2;
  OT*          C    = z == 0 ? C0 : z == 1 ? C1 : C2;

  const int tid = threadIdx.x;
  const int lane = tid & 63, wave = tid >> 6;
  const int quad = lane >> 4, l16 = lane & 15;
  const int bm = blockIdx.y * 128, bn = blockIdx.x * 128;
  const int wm = (wave >> 1) * 64, wn = (wave & 1) * 64;

  f32x4 acc[4][4] = {};

  for (int k0 = 0; k0 < K; k0 += 64) {
    __syncthreads();
#pragma unroll
    for (int hh = 0; hh < 2; ++hh) {
#pragma unroll
      for (int i = 0; i < 2; ++i) {
        const int nbase = wave * 128 + i * 64;       // wave-uniform
        const int n = nbase + lane;                  // per-lane chunk
        const int row = n >> 2, kc = (n & 3) * 8;
        gld16(&lB[hh][0][0] + (long)nbase * 8,
              &Bt[(long)(bn + row) * K + k0 + hh * 32 + kc]);
        if constexpr (__is_same(AT, bf16))
          gld16(&lA[hh][0][0] + (long)nbase * 8,
                &A[(long)(bm + row) * K + k0 + hh * 32 + kc]);
      }
      if constexpr (!__is_same(AT, bf16)) {
#pragma unroll
        for (int i = 0; i < 2; ++i) {
          int c = tid + i * 256;
          int row = c >> 2, kc = (c & 3) * 8;
          *(bf16x8*)&lA[hh][row][kc] =
              load8(&A[(long)(bm + row) * K + k0 + hh * 32 + kc]);
        }
      }
    }
    __syncthreads();  // compiler drains vmcnt+lgkmcnt here
#pragma unroll
    for (int hh = 0; hh < 2; ++hh) {
      bf16x8 af[4], bfr[4];
#pragma unroll
      for (int i = 0; i < 4; ++i) {
        af[i]  = *(const bf16x8*)&lA[hh][wm + i * 16 + l16][quad * 8];
        bfr[i] = *(const bf16x8*)&lB[hh][wn + i * 16 + l16][quad * 8];
      }
#pragma unroll
      for (int mi = 0; mi < 4; ++mi)
#pragma unroll
        for (int ni = 0; ni < 4; ++ni)
          acc[mi][ni] = __builtin_amdgcn_mfma_f32_16x16x32_bf16(
              af[mi], bfr[ni], acc[mi][ni], 0, 0, 0);
    }
  }

  // epilogue: C/D layout col=lane&15, row=quad*4+reg (m89-verified)
#pragma unroll
  for (int mi = 0; mi < 4; ++mi)
#pragma unroll
    for (int ni = 0; ni < 4; ++ni) {
      int col = bn + wn + ni * 16 + l16;
      float bv = bias[col];
#pragma unroll
      for (int r = 0; r < 4; ++r) {
        int row = bm + wm + mi * 16 + quad * 4 + r;
        C[(long)row * N + col] = (OT)(acc[mi][ni][r] + bv);
      }
    }
}

// ---------------------------------------------------------------------------
// Final GEMM: 128x64 tiles (512 blocks = 2/CU), BK=64 half-buffer staging.
// ---------------------------------------------------------------------------
__global__ __launch_bounds__(256) void gemm_bt_64(const bf16* __restrict__ A,
                                                  const bf16* __restrict__ Bt,
                                                  const float* __restrict__ bias,
                                                  float* __restrict__ C,
                                                  int M, int N, int K) {
  __shared__ bf16 lA[2][128][32];
  __shared__ bf16 lB[2][64][32];
  const int tid = threadIdx.x;
  const int lane = tid & 63, wave = tid >> 6;
  const int quad = lane >> 4, l16 = lane & 15;
  const int bm = blockIdx.y * 128, bn = blockIdx.x * 64;
  const int wm = (wave >> 1) * 64, wn = (wave & 1) * 32;

  f32x4 acc[4][2] = {};

  for (int k0 = 0; k0 < K; k0 += 64) {
    __syncthreads();
#pragma unroll
    for (int hh = 0; hh < 2; ++hh) {
#pragma unroll
      for (int i = 0; i < 2; ++i) {
        const int nbase = wave * 128 + i * 64;
        const int n = nbase + lane;
        const int row = n >> 2, kc = (n & 3) * 8;
        gld16(&lA[hh][0][0] + (long)nbase * 8,
              &A[(long)(bm + row) * K + k0 + hh * 32 + kc]);
      }
      {
        const int nbase = wave * 64;
        const int n = nbase + lane;
        const int row = n >> 2, kc = (n & 3) * 8;
        gld16(&lB[hh][0][0] + (long)nbase * 8,
              &Bt[(long)(bn + row) * K + k0 + hh * 32 + kc]);
      }
    }
    __syncthreads();
#pragma unroll
    for (int hh = 0; hh < 2; ++hh) {
      bf16x8 af[4], bfr[2];
#pragma unroll
      for (int i = 0; i < 4; ++i)
        af[i] = *(const bf16x8*)&lA[hh][wm + i * 16 + l16][quad * 8];
#pragma unroll
      for (int i = 0; i < 2; ++i)
        bfr[i] = *(const bf16x8*)&lB[hh][wn + i * 16 + l16][quad * 8];
#pragma unroll
      for (int mi = 0; mi < 4; ++mi)
#pragma unroll
        for (int ni = 0; ni < 2; ++ni)
          acc[mi][ni] = __builtin_amdgcn_mfma_f32_16x16x32_bf16(
              af[mi], bfr[ni], acc[mi][ni], 0, 0, 0);
    }
  }

#pragma unroll
  for (int mi = 0; mi < 4; ++mi)
#pragma unroll
    for (int ni = 0; ni < 2; ++ni) {
      int col = bn + wn + ni * 16 + l16;
      float bv = bias[col];
#pragma unroll
      for (int r = 0; r < 4; ++r) {
        int row = bm + wm + mi * 16 + quad * 4 + r;
        C[(long)row * N + col] = acc[mi][ni][r] + bv;
      }
    }
}

// ---------------------------------------------------------------------------
// Flash attention v6: split-K restructure of R12's v5.
// R15 theory: v5's qtA/qtB pairing left 33% of wave-steps idle (group A idles
// for kt>qtA) and grid 512 gave only 2 blocks/CU -> 30% occupancy, MfmaUtil
// 13.8% (latency-bound). v6: one 64-row q-tile per block, 8 waves; waves 0-3
// take EVEN 64-key tiles, waves 4-7 ODD tiles from a shared single-buffered
// 128-key stage. No-max exp2 softmax => partials merge by pure addition at
// the end (LDS bounce). Wave-step efficiency 67%->97%, grid 512->1024
// (3 co-resident/CU by LDS). Keeps: 64 keys/wave-step (R13/R14 lesson),
// XOR swizzle, reg-prefetch T14, per-lane softmax. Adds: setprio around
// MFMA clusters (T5). Barrier rate unchanged (2 per 128 keys).
// ---------------------------------------------------------------------------
#define SCALE_LOG2E 0.1803368801111244f  // (1/8) * log2(e)

__device__ inline void attn_step6(bool diag, int qloc, int quad, int l16, int g,
                                  const bf16 (*lKb)[64], const bf16 (*lVb)[128],
                                  bf16 (*lpw)[72], const bf16x8* aq,
                                  f32x4* o, float& l_s) {
  const int sw = l16 & 7;
  f32x4 s[4];
  __builtin_amdgcn_s_setprio(1);
#pragma unroll
  for (int ni = 0; ni < 4; ++ni) {
    f32x4 a = {};
#pragma unroll
    for (int c = 0; c < 2; ++c) {
      bf16x8 kf =
          *(const bf16x8*)&lKb[g * 64 + ni * 16 + l16][((c * 4 + quad) ^ sw) * 8];
      a = __builtin_amdgcn_mfma_f32_16x16x32_bf16(kf, aq[c], a, 0, 0, 0);
    }
    s[ni] = a * SCALE_LOG2E;
  }
  __builtin_amdgcn_s_setprio(0);
  if (diag) {
#pragma unroll
    for (int ni = 0; ni < 4; ++ni)
#pragma unroll
      for (int r = 0; r < 4; ++r)
        if (ni * 16 + quad * 4 + r > qloc) s[ni][r] = -1e9f;  // exp2 -> 0
  }
  float rs = 0.f;
#pragma unroll
  for (int ni = 0; ni < 4; ++ni) {
    bf16x4 p4;
#pragma unroll
    for (int r = 0; r < 4; ++r) {
      float p = exp2g(s[ni][r]);
      p4[r] = (bf16)p;
      rs += p;
    }
    *(bf16x4*)&lpw[l16][ni * 16 + quad * 4] = p4;  // P[q][key], packed b64
  }
  l_s += rs;
  __builtin_amdgcn_s_setprio(1);
#pragma unroll
  for (int c = 0; c < 2; ++c) {
    bf16x8 ap = *(const bf16x8*)&lpw[l16][c * 32 + quad * 8];
#pragma unroll
    for (int di = 0; di < 4; ++di) {
      bf16x8 vf =
          *(const bf16x8*)&lVb[di * 16 + l16][g * 64 + ((c * 4 + quad) ^ sw) * 8];
      o[di] = __builtin_amdgcn_mfma_f32_16x16x32_bf16(vf, ap, o[di], 0, 0, 0);
    }
  }
  __builtin_amdgcn_s_setprio(0);
}

__device__ inline void store_o(bf16* Ob, int qrow, int lane, int quad, int l16,
                               bf16 (*lpw)[72], const f32x4* o, float l_s) {
  float rs = l_s;
  rs += __shfl_xor(rs, 16);
  rs += __shfl_xor(rs, 32);
  const float inv = 1.0f / rs;
#pragma unroll
  for (int di = 0; di < 4; ++di) {
    bf16x4 p4;
#pragma unroll
    for (int r = 0; r < 4; ++r) p4[r] = (bf16)(o[di][r] * inv);
    *(bf16x4*)&lpw[l16][di * 16 + quad * 4] = p4;
  }
  const int q = lane >> 2, db = (lane & 3) * 16;
  bf16x8 v0 = *(const bf16x8*)&lpw[q][db];
  bf16x8 v1 = *(const bf16x8*)&lpw[q][db + 8];
  *(bf16x8*)&Ob[(long)(qrow + q) * D_ + db] = v0;
  *(bf16x8*)&Ob[(long)(qrow + q) * D_ + db + 8] = v1;
}

__global__ __launch_bounds__(512) void flash_attn6(const bf16* __restrict__ Q,
                                                   const bf16* __restrict__ K,
                                                   const bf16* __restrict__ VT,
                                                   bf16* __restrict__ O) {
  // 128-key single-buffered stage (32 KB), reused as fp32 merge scratch after
  // the loop. lp (18 KB) stays separate. Total LDS 50 KB -> 3 blocks/CU.
  __shared__ __align__(16) union {
    struct { bf16 K[128][64]; bf16 VT[64][128]; } s;  // chunk-col XOR-swizzled
    struct { float o[4][16][68]; float l[4][64]; } m; // group-B partials
  } u;
  __shared__ bf16 lp[8][16][72];  // per-wave P / O bounce
  const int tid = threadIdx.x;
  const int lane = tid & 63, wave = tid >> 6;  // 0..7
  const int quad = lane >> 4, l16 = lane & 15;
  const int qt = 31 - blockIdx.x;  // longest blocks dispatch first
  const int bh = blockIdx.y;
  const bool isB = wave >= 4;
  const int g = isB ? 1 : 0;  // key-tile parity owned by this wave's group
  const int w4 = wave & 3;
  const int b = bh >> 4, h = bh & 15;
  const bf16* Qb = Q + (long)b * S_ * D_ + h * HD_;
  const bf16* Kb = K + (long)b * S_ * D_ + h * HD_;
  const bf16* Vb = VT + (long)bh * HD_ * S_;
  const int qrow = qt * 64 + w4 * 16;   // waves w and w+4 share the same rows
  const int qloc = w4 * 16 + l16;

  bf16x8 aq[2];
#pragma unroll
  for (int c = 0; c < 2; ++c)
    aq[c] = *(const bf16x8*)&Qb[(long)(qrow + l16) * D_ + c * 32 + quad * 8];

  f32x4 o[4] = {};
  float l_s = 0.f;

  // staging geometry: 1024 K-chunks (128 rows x 8) + 1024 VT-chunks (64 x 16)
  const int kr0 = tid >> 3, kc0 = tid & 7;   // K rows 0..63 (+64 for 2nd)
  const int vr0 = tid >> 4, vc0 = tid & 15;  // VT rows 0..31 (+32 for 2nd)
  const int ksw = (kc0 ^ (kr0 & 7)) * 8;     // (kr0+64)&7 == kr0&7
  const int vsw = (((vc0 & 7) ^ (vr0 & 7)) + (vc0 >> 3) * 8) * 8;

  bf16x8 rk0, rk1, rv0, rv1;
  const int nt = qt + 1;            // causal 64-key tiles for this q-tile
  const int nit = (nt + 1) >> 1;    // 128-key iterations

  // prologue: stage iteration 0
  rk0 = *(const bf16x8*)&Kb[(long)kr0 * D_ + kc0 * 8];
  rk1 = *(const bf16x8*)&Kb[(long)(kr0 + 64) * D_ + kc0 * 8];
  rv0 = *(const bf16x8*)&Vb[(long)vr0 * S_ + vc0 * 8];
  rv1 = *(const bf16x8*)&Vb[(long)(vr0 + 32) * S_ + vc0 * 8];
  *(bf16x8*)&u.s.K[kr0][ksw] = rk0;
  *(bf16x8*)&u.s.K[kr0 + 64][ksw] = rk1;
  *(bf16x8*)&u.s.VT[vr0][vsw] = rv0;
  *(bf16x8*)&u.s.VT[vr0 + 32][vsw] = rv1;
  __syncthreads();

  for (int it = 0; it < nit; ++it) {
    if (it + 1 < nit) {  // T14: issue next 128 keys early, commit after barrier
      const long k0 = (long)(it + 1) * 128;
      rk0 = *(const bf16x8*)&Kb[(k0 + kr0) * D_ + kc0 * 8];
      rk1 = *(const bf16x8*)&Kb[(k0 + kr0 + 64) * D_ + kc0 * 8];
      rv0 = *(const bf16x8*)&Vb[(long)vr0 * S_ + k0 + vc0 * 8];
      rv1 = *(const bf16x8*)&Vb[(long)(vr0 + 32) * S_ + k0 + vc0 * 8];
    }
    const int tile = 2 * it + g;
    if (tile < nt)  // group B idles only on the last iter when nt is odd
      attn_step6(tile == qt, qloc, quad, l16, g, u.s.K, u.s.VT, lp[wave], aq,
                 o, l_s);
    __syncthreads();  // all waves done reading the stage
    if (it + 1 < nit) {
      *(bf16x8*)&u.s.K[kr0][ksw] = rk0;
      *(bf16x8*)&u.s.K[kr0 + 64][ksw] = rk1;
      *(bf16x8*)&u.s.VT[vr0][vsw] = rv0;
      *(bf16x8*)&u.s.VT[vr0 + 32][vsw] = rv1;
      __syncthreads();
    }
  }

  // merge group-B partials into group A (pure addition: no-max softmax)
  if (isB) {
#pragma unroll
    for (int di = 0; di < 4; ++di)
      *(f32x4*)&u.m.o[w4][l16][di * 16 + quad * 4] = o[di];
    u.m.l[w4][lane] = l_s;
  }
  __syncthreads();
  if (!isB) {
    l_s += u.m.l[w4][lane];
#pragma unroll
    for (int di = 0; di < 4; ++di)
      o[di] += *(const f32x4*)&u.m.o[w4][l16][di * 16 + quad * 4];
    bf16* Ob = O + (long)b * S_ * D_ + h * HD_;
    store_o(Ob, qrow, lane, quad, l16, lp[wave], o, l_s);
  }
}

// ---------------------------------------------------------------------------
extern "C" void kernel_launch(void* const* d_in, const int* in_sizes, int n_in,
                              void* d_out, int out_size, void* d_ws, size_t ws_size,
                              hipStream_t stream) {
  (void)in_sizes; (void)n_in; (void)out_size;
  const float* q_in = (const float*)d_in[0];
  const float* k_in = (const float*)d_in[1];
  const float* v_in = (const float*)d_in[2];
  const float* Wq   = (const float*)d_in[3];
  const float* bq   = (const float*)d_in[4];
  const float* Wk   = (const float*)d_in[5];
  const float* bk   = (const float*)d_in[6];
  const float* Wv   = (const float*)d_in[7];
  const float* bv   = (const float*)d_in[8];
  const float* Wo   = (const float*)d_in[9];
  const float* bo   = (const float*)d_in[10];
  float* out = (float*)d_out;  // reference output dtype is float32

  bf16* ws = (bf16*)d_ws;
  const size_t WSZ = (size_t)D_ * D_;       // 1M elements
  const size_t TSZ = (size_t)B_ * S_ * D_;  // 4M elements
  bf16* WqT = ws;
  bf16* WkT = WqT + WSZ;
  bf16* WvT = WkT + WSZ;
  bf16* WoT = WvT + WSZ;
  bf16* Qp  = WoT + WSZ;
  bf16* Kp  = Qp + TSZ;
  bf16* Vp  = Kp + TSZ;
  bf16* VTp = Vp + TSZ;
  bf16* Ap  = VTp + TSZ;   // 48 MB used through here (validated R2-R14)
  // converted inputs: lifetimes end before VTp/Ap are written -> overlap
  bf16* Xq  = VTp;
  bf16* Xk  = Ap;
  bf16* Xv  = Ap + TSZ;    // needs ws_size >= 56 MB (validated R8-R14)
  const bool pre = ws_size >= (4 * WSZ + 6 * TSZ) * sizeof(bf16);

  dim3 blk(256);
  transpose_w<<<dim3(32, 32, pre ? 16 : 4), blk, 0, stream>>>(
      Wq, Wk, Wv, Wo, WqT, WkT, WvT, WoT, q_in, k_in, v_in, Xq, Xk, Xv);

  if (pre)
    gemm_bt_dma<bf16, bf16><<<dim3(8, 32, 3), blk, 0, stream>>>(
        Xq, Xk, Xv, WqT, WkT, WvT, bq, bk, bv, Qp, Kp, Vp, MM, D_, D_);
  else
    gemm_bt_dma<float, bf16><<<dim3(8, 32, 3), blk, 0, stream>>>(
        q_in, k_in, v_in, WqT, WkT, WvT, bq, bk, bv, Qp, Kp, Vp, MM, D_, D_);

  transpose_v64<<<dim3(S_ / 64, B_ * H_), blk, 0, stream>>>(Vp, VTp);

  flash_attn6<<<dim3(32, B_ * H_), dim3(512), 0, stream>>>(Qp, Kp, VTp, Ap);

  gemm_bt_64<<<dim3(16, 32), blk, 0, stream>>>(Ap, WoT, bo, out, MM, D_, D_);
}

// Round 2
// 214.916 us; speedup vs baseline: 1.1243x; 1.1243x over previous
//
#include <hip/hip_runtime.h>

#define B_  2
#define S_  2048
#define D_  1024
#define H_  16
#define HD_ 64
#define MM  (B_ * S_)  // 4096 rows in all projection GEMMs

typedef __bf16 bf16;
typedef __attribute__((ext_vector_type(8))) __bf16 bf16x8;
typedef __attribute__((ext_vector_type(4))) __bf16 bf16x4;
typedef __attribute__((ext_vector_type(4))) float  f32x4;

// exp2 via the native v_exp_f32 (computes 2^x). Avoids glibc __exp2f macro.
__device__ inline float exp2g(float x) { return __builtin_amdgcn_exp2f(x); }

// Load 8 contiguous elements as bf16x8 (converting if fp32).
__device__ inline bf16x8 load8(const bf16* p) { return *(const bf16x8*)p; }
__device__ inline bf16x8 load8(const float* p) {
  float4 a = *(const float4*)p;
  float4 b = *(const float4*)(p + 4);
  bf16x8 r;
  r[0] = (bf16)a.x; r[1] = (bf16)a.y; r[2] = (bf16)a.z; r[3] = (bf16)a.w;
  r[4] = (bf16)b.x; r[5] = (bf16)b.y; r[6] = (bf16)b.z; r[7] = (bf16)b.w;
  return r;
}

// Async global->LDS DMA, 16 B per lane (dest = wave-uniform base + lane*16).
__device__ inline void gld16(void* lds, const void* g) {
  __builtin_amdgcn_global_load_lds(
      (const __attribute__((address_space(1))) unsigned int*)g,
      (__attribute__((address_space(3))) unsigned int*)lds, 16, 0, 0);
}

// ---------------------------------------------------------------------------
// z 0..3: 32x32-tiled weight transpose fp32->bf16.
// z 4..15: bulk fp32->bf16 convert of q_in/k_in/v_in (1M elems per plane).
// ---------------------------------------------------------------------------
__global__ __launch_bounds__(256) void transpose_w(
    const float* __restrict__ W0, const float* __restrict__ W1,
    const float* __restrict__ W2, const float* __restrict__ W3,
    bf16* __restrict__ T0, bf16* __restrict__ T1,
    bf16* __restrict__ T2, bf16* __restrict__ T3,
    const float* __restrict__ X0, const float* __restrict__ X1,
    const float* __restrict__ X2,
    bf16* __restrict__ Y0, bf16* __restrict__ Y1, bf16* __restrict__ Y2) {
  const int z = blockIdx.z;
  if (z >= 4) {  // convert plane
    const int p = z - 4, t = p >> 2;
    const float* src = t == 0 ? X0 : t == 1 ? X1 : X2;
    bf16* dst = t == 0 ? Y0 : t == 1 ? Y1 : Y2;
    long base = ((long)(p & 3) << 20) +
                (long)(blockIdx.y * 32 + blockIdx.x) * 1024 + threadIdx.x * 4;
    float4 v = *(const float4*)&src[base];
    bf16x4 o4;
    o4[0] = (bf16)v.x; o4[1] = (bf16)v.y; o4[2] = (bf16)v.z; o4[3] = (bf16)v.w;
    *(bf16x4*)&dst[base] = o4;
    return;
  }
  __shared__ bf16 t[32][40];
  const float* in = z == 0 ? W0 : z == 1 ? W1 : z == 2 ? W2 : W3;
  bf16* out = z == 0 ? T0 : z == 1 ? T1 : z == 2 ? T2 : T3;
  const int tx = threadIdx.x & 31;
  const int ty = threadIdx.x >> 5;  // 0..7
  const int r0 = blockIdx.y * 32, c0 = blockIdx.x * 32;
#pragma unroll
  for (int j = 0; j < 32; j += 8)
    t[ty + j][tx] = (bf16)in[(long)(r0 + ty + j) * D_ + (c0 + tx)];
  __syncthreads();
#pragma unroll
  for (int j = 0; j < 32; j += 8)
    out[(long)(c0 + ty + j) * D_ + (r0 + tx)] = t[tx][ty + j];
}

// ---------------------------------------------------------------------------
// V [B,S,H,HD] (bf16) -> VT [B,H,HD,S]  (coalesced LDS-bounce transpose)
// ---------------------------------------------------------------------------
__global__ __launch_bounds__(256) void transpose_v64(const bf16* __restrict__ V,
                                                     bf16* __restrict__ VT) {
  __shared__ bf16 t[64][72];
  const int tid = threadIdx.x;
  const int s0 = blockIdx.x * 64;
  const int bh = blockIdx.y;
  const int b = bh >> 4, h = bh & 15;
  const bf16* ip = V + (long)b * S_ * D_ + h * HD_;
  bf16* op = VT + (long)bh * HD_ * S_;
#pragma unroll
  for (int i = 0; i < 2; ++i) {
    int c = tid + i * 256;
    int r = c >> 3, cc = (c & 7) * 8;
    *(bf16x8*)&t[r][cc] = *(const bf16x8*)&ip[(long)(s0 + r) * D_ + cc];
  }
  __syncthreads();
#pragma unroll
  for (int i = 0; i < 2; ++i) {
    int c = tid + i * 256;
    int d = c >> 3, sc = (c & 7) * 8;
    bf16x8 v;
#pragma unroll
    for (int j = 0; j < 8; ++j) v[j] = t[sc + j][d];
    *(bf16x8*)&op[(long)d * S_ + s0 + sc] = v;
  }
}

// ---------------------------------------------------------------------------
// Batched C[M,N] = A[M,K] @ Bt[N,K]^T + bias[N], z selects operand triple.
// BK=64 via two [128][32] half-buffers (keeps 64B-stride conflict-free
// fragment reads and DMA lane-contiguity); halves barrier count vs R12.
// R16: XCD-aware swizzle (XCD = dispatch_id % 8, id = bx + 8*by per z-plane):
// each XCD gets 4 contiguous bm-panels x all bn -> A 1MB + B 2MB L2-resident.
// ---------------------------------------------------------------------------
template <typename AT, typename OT>
__global__ __launch_bounds__(256) void gemm_bt_dma(
    const AT* __restrict__ A0, const AT* __restrict__ A1, const AT* __restrict__ A2,
    const bf16* __restrict__ B0, const bf16* __restrict__ B1, const bf16* __restrict__ B2,
    const float* __restrict__ c0, const float* __restrict__ c1, const float* __restrict__ c2,
    OT* __restrict__ C0, OT* __restrict__ C1, OT* __restrict__ C2,
    int M, int N, int K) {
  __shared__ bf16 lA[2][128][32];
  __shared__ bf16 lB[2][128][32];
  const int z = blockIdx.z;
  const AT*    A    = z == 0 ? A0 : z == 1 ? A1 : A2;
  const bf16*  Bt   = z == 0 ? B0 : z == 1 ? B1 : B2;
  const float* bias = z == 0 ? c0 : z == 1 ? c1 : c2;
  OT*          C    = z == 0 ? C0 : z == 1 ? C1 : C2;

  const int tid = threadIdx.x;
  const int lane = tid & 63, wave = tid >> 6;
  const int quad = lane >> 4, l16 = lane & 15;
  // bijective XCD swizzle within the 256-block z-plane (256 % 8 == 0)
  const int id = blockIdx.x + (blockIdx.y << 3);
  const int nid = (id & 7) * 32 + (id >> 3);
  const int bm = (nid >> 3) * 128, bn = (nid & 7) * 128;
  const int wm = (wave >> 1) * 64, wn = (wave & 1) * 64;

  f32x4 acc[4][4] = {};

  for (int k0 = 0; k0 < K; k0 += 64) {
    __syncthreads();
#pragma unroll
    for (int hh = 0; hh < 2; ++hh) {
#pragma unroll
      for (int i = 0; i < 2; ++i) {
        const int nbase = wave * 128 + i * 64;       // wave-uniform
        const int n = nbase + lane;                  // per-lane chunk
        const int row = n >> 2, kc = (n & 3) * 8;
        gld16(&lB[hh][0][0] + (long)nbase * 8,
              &Bt[(long)(bn + row) * K + k0 + hh * 32 + kc]);
        if constexpr (__is_same(AT, bf16))
          gld16(&lA[hh][0][0] + (long)nbase * 8,
                &A[(long)(bm + row) * K + k0 + hh * 32 + kc]);
      }
      if constexpr (!__is_same(AT, bf16)) {
#pragma unroll
        for (int i = 0; i < 2; ++i) {
          int c = tid + i * 256;
          int row = c >> 2, kc = (c & 3) * 8;
          *(bf16x8*)&lA[hh][row][kc] =
              load8(&A[(long)(bm + row) * K + k0 + hh * 32 + kc]);
        }
      }
    }
    __syncthreads();  // compiler drains vmcnt+lgkmcnt here
#pragma unroll
    for (int hh = 0; hh < 2; ++hh) {
      bf16x8 af[4], bfr[4];
#pragma unroll
      for (int i = 0; i < 4; ++i) {
        af[i]  = *(const bf16x8*)&lA[hh][wm + i * 16 + l16][quad * 8];
        bfr[i] = *(const bf16x8*)&lB[hh][wn + i * 16 + l16][quad * 8];
      }
#pragma unroll
      for (int mi = 0; mi < 4; ++mi)
#pragma unroll
        for (int ni = 0; ni < 4; ++ni)
          acc[mi][ni] = __builtin_amdgcn_mfma_f32_16x16x32_bf16(
              af[mi], bfr[ni], acc[mi][ni], 0, 0, 0);
    }
  }

  // epilogue: C/D layout col=lane&15, row=quad*4+reg (m89-verified)
#pragma unroll
  for (int mi = 0; mi < 4; ++mi)
#pragma unroll
    for (int ni = 0; ni < 4; ++ni) {
      int col = bn + wn + ni * 16 + l16;
      float bv = bias[col];
#pragma unroll
      for (int r = 0; r < 4; ++r) {
        int row = bm + wm + mi * 16 + quad * 4 + r;
        C[(long)row * N + col] = (OT)(acc[mi][ni][r] + bv);
      }
    }
}

// ---------------------------------------------------------------------------
// Final GEMM: 128x64 tiles (512 blocks = 2/CU), BK=64 half-buffer staging.
// R16: XCD swizzle (512 % 8 == 0): each XCD gets 4 bm-panels x all 16 bn
// -> A 1MB + B (WoT) 2MB L2-resident.
// ---------------------------------------------------------------------------
__global__ __launch_bounds__(256) void gemm_bt_64(const bf16* __restrict__ A,
                                                  const bf16* __restrict__ Bt,
                                                  const float* __restrict__ bias,
                                                  float* __restrict__ C,
                                                  int M, int N, int K) {
  __shared__ bf16 lA[2][128][32];
  __shared__ bf16 lB[2][64][32];
  const int tid = threadIdx.x;
  const int lane = tid & 63, wave = tid >> 6;
  const int quad = lane >> 4, l16 = lane & 15;
  const int id = blockIdx.x + (blockIdx.y << 4);
  const int nid = (id & 7) * 64 + (id >> 3);
  const int bm = (nid >> 4) * 128, bn = (nid & 15) * 64;
  const int wm = (wave >> 1) * 64, wn = (wave & 1) * 32;

  f32x4 acc[4][2] = {};

  for (int k0 = 0; k0 < K; k0 += 64) {
    __syncthreads();
#pragma unroll
    for (int hh = 0; hh < 2; ++hh) {
#pragma unroll
      for (int i = 0; i < 2; ++i) {
        const int nbase = wave * 128 + i * 64;
        const int n = nbase + lane;
        const int row = n >> 2, kc = (n & 3) * 8;
        gld16(&lA[hh][0][0] + (long)nbase * 8,
              &A[(long)(bm + row) * K + k0 + hh * 32 + kc]);
      }
      {
        const int nbase = wave * 64;
        const int n = nbase + lane;
        const int row = n >> 2, kc = (n & 3) * 8;
        gld16(&lB[hh][0][0] + (long)nbase * 8,
              &Bt[(long)(bn + row) * K + k0 + hh * 32 + kc]);
      }
    }
    __syncthreads();
#pragma unroll
    for (int hh = 0; hh < 2; ++hh) {
      bf16x8 af[4], bfr[2];
#pragma unroll
      for (int i = 0; i < 4; ++i)
        af[i] = *(const bf16x8*)&lA[hh][wm + i * 16 + l16][quad * 8];
#pragma unroll
      for (int i = 0; i < 2; ++i)
        bfr[i] = *(const bf16x8*)&lB[hh][wn + i * 16 + l16][quad * 8];
#pragma unroll
      for (int mi = 0; mi < 4; ++mi)
#pragma unroll
        for (int ni = 0; ni < 2; ++ni)
          acc[mi][ni] = __builtin_amdgcn_mfma_f32_16x16x32_bf16(
              af[mi], bfr[ni], acc[mi][ni], 0, 0, 0);
    }
  }

#pragma unroll
  for (int mi = 0; mi < 4; ++mi)
#pragma unroll
    for (int ni = 0; ni < 2; ++ni) {
      int col = bn + wn + ni * 16 + l16;
      float bv = bias[col];
#pragma unroll
      for (int r = 0; r < 4; ++r) {
        int row = bm + wm + mi * 16 + quad * 4 + r;
        C[(long)row * N + col] = acc[mi][ni][r] + bv;
      }
    }
}

// ---------------------------------------------------------------------------
// Flash attention v7 = v5's exact double-buffered pipeline with ADJACENT
// q-tile pairing. R15 post-mortem: v6's split-K halved nit_max but 2.8x'd
// per-iteration latency (serialized single-buffer stage + write conflicts).
// v7 keeps v5's loop byte-for-byte and only changes which q-tiles the two
// wave groups own: (2x, 2x+1) instead of (x, 31-x). Both groups are active
// every iteration except the last (97% wave-step efficiency vs 67%); total
// staged tiles per bh drop 392 -> 272 (-30% LDS/softmax/stage work).
// bh>=16 blocks take the reversed pairing (30-2x, 31-2x) so co-resident
// block pairs (ids i and i+256, same x) sum to a constant 34 iterations.
// ---------------------------------------------------------------------------
#define SCALE_LOG2E 0.1803368801111244f  // (1/8) * log2(e)

__device__ inline void attn_step5(bool diag, int qloc, int quad, int l16,
                                  const bf16 (*lKb)[64], const bf16 (*lVb)[64],
                                  bf16 (*lpw)[72], const bf16x8* aq,
                                  f32x4* o, float& l_s) {
  const int sw = l16 & 7;
  f32x4 s[4];
#pragma unroll
  for (int ni = 0; ni < 4; ++ni) {
    f32x4 a = {};
#pragma unroll
    for (int c = 0; c < 2; ++c) {
      bf16x8 kf = *(const bf16x8*)&lKb[ni * 16 + l16][((c * 4 + quad) ^ sw) * 8];
      a = __builtin_amdgcn_mfma_f32_16x16x32_bf16(kf, aq[c], a, 0, 0, 0);
    }
    s[ni] = a * SCALE_LOG2E;
  }
  if (diag) {
#pragma unroll
    for (int ni = 0; ni < 4; ++ni)
#pragma unroll
      for (int r = 0; r < 4; ++r)
        if (ni * 16 + quad * 4 + r > qloc) s[ni][r] = -1e9f;  // exp2 -> 0
  }
  float rs = 0.f;
#pragma unroll
  for (int ni = 0; ni < 4; ++ni) {
    bf16x4 p4;
#pragma unroll
    for (int r = 0; r < 4; ++r) {
      float p = exp2g(s[ni][r]);
      p4[r] = (bf16)p;
      rs += p;
    }
    *(bf16x4*)&lpw[l16][ni * 16 + quad * 4] = p4;  // P[q][key], packed b64
  }
  l_s += rs;
#pragma unroll
  for (int c = 0; c < 2; ++c) {
    bf16x8 ap = *(const bf16x8*)&lpw[l16][c * 32 + quad * 8];
#pragma unroll
    for (int di = 0; di < 4; ++di) {
      bf16x8 vf = *(const bf16x8*)&lVb[di * 16 + l16][((c * 4 + quad) ^ sw) * 8];
      o[di] = __builtin_amdgcn_mfma_f32_16x16x32_bf16(vf, ap, o[di], 0, 0, 0);
    }
  }
}

__device__ inline void store_o(bf16* Ob, int qrow, int lane, int quad, int l16,
                               bf16 (*lpw)[72], const f32x4* o, float l_s) {
  float rs = l_s;
  rs += __shfl_xor(rs, 16);
  rs += __shfl_xor(rs, 32);
  const float inv = 1.0f / rs;
#pragma unroll
  for (int di = 0; di < 4; ++di) {
    bf16x4 p4;
#pragma unroll
    for (int r = 0; r < 4; ++r) p4[r] = (bf16)(o[di][r] * inv);
    *(bf16x4*)&lpw[l16][di * 16 + quad * 4] = p4;
  }
  const int q = lane >> 2, db = (lane & 3) * 16;
  bf16x8 v0 = *(const bf16x8*)&lpw[q][db];
  bf16x8 v1 = *(const bf16x8*)&lpw[q][db + 8];
  *(bf16x8*)&Ob[(long)(qrow + q) * D_ + db] = v0;
  *(bf16x8*)&Ob[(long)(qrow + q) * D_ + db + 8] = v1;
}

__global__ __launch_bounds__(512) void flash_attn7(const bf16* __restrict__ Q,
                                                   const bf16* __restrict__ K,
                                                   const bf16* __restrict__ VT,
                                                   bf16* __restrict__ O) {
  __shared__ bf16 lK[2][64][64];   // [key][dim], chunk-col XOR-swizzled
  __shared__ bf16 lV[2][64][64];   // [dim][key], chunk-col XOR-swizzled
  __shared__ bf16 lp[8][16][72];   // per-wave P / O bounce
  const int tid = threadIdx.x;
  const int lane = tid & 63, wave = tid >> 6;  // 0..7
  const int quad = lane >> 4, l16 = lane & 15;
  const int x = blockIdx.x, bh = blockIdx.y;
  // adjacent pairing; reversed in the upper bh half for per-CU load balance
  const bool flip = (bh & 16) != 0;
  const int qtA = flip ? 30 - 2 * x : 2 * x;
  const int qtB = qtA + 1;
  const bool isB = wave >= 4;
  const int w4 = wave & 3;
  const int myqt = isB ? qtB : qtA;
  const int b = bh >> 4, h = bh & 15;
  const bf16* Qb = Q + (long)b * S_ * D_ + h * HD_;
  const bf16* Kb = K + (long)b * S_ * D_ + h * HD_;
  const bf16* Vb = VT + (long)bh * HD_ * S_;
  const int qrow = myqt * 64 + w4 * 16;
  const int qloc = w4 * 16 + l16;

  bf16x8 aq[2];
#pragma unroll
  for (int c = 0; c < 2; ++c)
    aq[c] = *(const bf16x8*)&Qb[(long)(qrow + l16) * D_ + c * 32 + quad * 8];

  f32x4 o[4] = {};
  float l_s = 0.f;

  const int srow = tid >> 3, scol = tid & 7;
  const int swcol = (scol ^ (srow & 7)) * 8;

  bf16x8 kreg, vreg;
  kreg = *(const bf16x8*)&Kb[(long)srow * D_ + scol * 8];
  vreg = *(const bf16x8*)&Vb[(long)srow * S_ + scol * 8];
  *(bf16x8*)&lK[0][srow][swcol] = kreg;
  *(bf16x8*)&lV[0][srow][swcol] = vreg;
  __syncthreads();

  const int ktMax = qtB;
  for (int kt = 0; kt <= ktMax; ++kt) {
    const int p = kt & 1;
    if (kt < ktMax) {
      const long k0 = (long)(kt + 1) * 64;
      kreg = *(const bf16x8*)&Kb[(k0 + srow) * D_ + scol * 8];
      vreg = *(const bf16x8*)&Vb[(long)srow * S_ + k0 + scol * 8];
    }
    if (isB || kt <= qtA)
      attn_step5(kt == myqt, qloc, quad, l16, lK[p], lV[p], lp[wave], aq,
                 o, l_s);
    if (kt < ktMax) {
      *(bf16x8*)&lK[1 - p][srow][swcol] = kreg;
      *(bf16x8*)&lV[1 - p][srow][swcol] = vreg;
      __syncthreads();
    }
  }

  bf16* Ob = O + (long)b * S_ * D_ + h * HD_;
  store_o(Ob, qrow, lane, quad, l16, lp[wave], o, l_s);
}

// ---------------------------------------------------------------------------
extern "C" void kernel_launch(void* const* d_in, const int* in_sizes, int n_in,
                              void* d_out, int out_size, void* d_ws, size_t ws_size,
                              hipStream_t stream) {
  (void)in_sizes; (void)n_in; (void)out_size;
  const float* q_in = (const float*)d_in[0];
  const float* k_in = (const float*)d_in[1];
  const float* v_in = (const float*)d_in[2];
  const float* Wq   = (const float*)d_in[3];
  const float* bq   = (const float*)d_in[4];
  const float* Wk   = (const float*)d_in[5];
  const float* bk   = (const float*)d_in[6];
  const float* Wv   = (const float*)d_in[7];
  const float* bv   = (const float*)d_in[8];
  const float* Wo   = (const float*)d_in[9];
  const float* bo   = (const float*)d_in[10];
  float* out = (float*)d_out;  // reference output dtype is float32

  bf16* ws = (bf16*)d_ws;
  const size_t WSZ = (size_t)D_ * D_;       // 1M elements
  const size_t TSZ = (size_t)B_ * S_ * D_;  // 4M elements
  bf16* WqT = ws;
  bf16* WkT = WqT + WSZ;
  bf16* WvT = WkT + WSZ;
  bf16* WoT = WvT + WSZ;
  bf16* Qp  = WoT + WSZ;
  bf16* Kp  = Qp + TSZ;
  bf16* Vp  = Kp + TSZ;
  bf16* VTp = Vp + TSZ;
  bf16* Ap  = VTp + TSZ;   // 48 MB used through here (validated R2-R14)
  // converted inputs: lifetimes end before VTp/Ap are written -> overlap
  bf16* Xq  = VTp;
  bf16* Xk  = Ap;
  bf16* Xv  = Ap + TSZ;    // needs ws_size >= 56 MB (validated R8-R14)
  const bool pre = ws_size >= (4 * WSZ + 6 * TSZ) * sizeof(bf16);

  dim3 blk(256);
  transpose_w<<<dim3(32, 32, pre ? 16 : 4), blk, 0, stream>>>(
      Wq, Wk, Wv, Wo, WqT, WkT, WvT, WoT, q_in, k_in, v_in, Xq, Xk, Xv);

  if (pre)
    gemm_bt_dma<bf16, bf16><<<dim3(8, 32, 3), blk, 0, stream>>>(
        Xq, Xk, Xv, WqT, WkT, WvT, bq, bk, bv, Qp, Kp, Vp, MM, D_, D_);
  else
    gemm_bt_dma<float, bf16><<<dim3(8, 32, 3), blk, 0, stream>>>(
        q_in, k_in, v_in, WqT, WkT, WvT, bq, bk, bv, Qp, Kp, Vp, MM, D_, D_);

  transpose_v64<<<dim3(S_ / 64, B_ * H_), blk, 0, stream>>>(Vp, VTp);

  flash_attn7<<<dim3(16, B_ * H_), dim3(512), 0, stream>>>(Qp, Kp, VTp, Ap);

  gemm_bt_64<<<dim3(16, 32), blk, 0, stream>>>(Ap, WoT, bo, out, MM, D_, D_);
}

// Round 3
// 205.325 us; speedup vs baseline: 1.1768x; 1.0467x over previous
//
#include <hip/hip_runtime.h>

#define B_  2
#define S_  2048
#define D_  1024
#define H_  16
#define HD_ 64
#define MM  (B_ * S_)  // 4096 rows in all projection GEMMs

typedef __bf16 bf16;
typedef __attribute__((ext_vector_type(8))) __bf16 bf16x8;
typedef __attribute__((ext_vector_type(4))) __bf16 bf16x4;
typedef __attribute__((ext_vector_type(4))) float  f32x4;

// exp2 via the native v_exp_f32 (computes 2^x). Avoids glibc __exp2f macro.
__device__ inline float exp2g(float x) { return __builtin_amdgcn_exp2f(x); }

// Load 8 contiguous elements as bf16x8 (converting if fp32).
__device__ inline bf16x8 load8(const bf16* p) { return *(const bf16x8*)p; }
__device__ inline bf16x8 load8(const float* p) {
  float4 a = *(const float4*)p;
  float4 b = *(const float4*)(p + 4);
  bf16x8 r;
  r[0] = (bf16)a.x; r[1] = (bf16)a.y; r[2] = (bf16)a.z; r[3] = (bf16)a.w;
  r[4] = (bf16)b.x; r[5] = (bf16)b.y; r[6] = (bf16)b.z; r[7] = (bf16)b.w;
  return r;
}

// Async global->LDS DMA, 16 B per lane (dest = wave-uniform base + lane*16).
__device__ inline void gld16(void* lds, const void* g) {
  __builtin_amdgcn_global_load_lds(
      (const __attribute__((address_space(1))) unsigned int*)g,
      (__attribute__((address_space(3))) unsigned int*)lds, 16, 0, 0);
}

// ---------------------------------------------------------------------------
// z 0..3: 32x32-tiled weight transpose fp32->bf16.
// z 4..15: bulk fp32->bf16 convert of q_in/k_in/v_in (1M elems per plane).
// ---------------------------------------------------------------------------
__global__ __launch_bounds__(256) void transpose_w(
    const float* __restrict__ W0, const float* __restrict__ W1,
    const float* __restrict__ W2, const float* __restrict__ W3,
    bf16* __restrict__ T0, bf16* __restrict__ T1,
    bf16* __restrict__ T2, bf16* __restrict__ T3,
    const float* __restrict__ X0, const float* __restrict__ X1,
    const float* __restrict__ X2,
    bf16* __restrict__ Y0, bf16* __restrict__ Y1, bf16* __restrict__ Y2) {
  const int z = blockIdx.z;
  if (z >= 4) {  // convert plane
    const int p = z - 4, t = p >> 2;
    const float* src = t == 0 ? X0 : t == 1 ? X1 : X2;
    bf16* dst = t == 0 ? Y0 : t == 1 ? Y1 : Y2;
    long base = ((long)(p & 3) << 20) +
                (long)(blockIdx.y * 32 + blockIdx.x) * 1024 + threadIdx.x * 4;
    float4 v = *(const float4*)&src[base];
    bf16x4 o4;
    o4[0] = (bf16)v.x; o4[1] = (bf16)v.y; o4[2] = (bf16)v.z; o4[3] = (bf16)v.w;
    *(bf16x4*)&dst[base] = o4;
    return;
  }
  __shared__ bf16 t[32][40];
  const float* in = z == 0 ? W0 : z == 1 ? W1 : z == 2 ? W2 : W3;
  bf16* out = z == 0 ? T0 : z == 1 ? T1 : z == 2 ? T2 : T3;
  const int tx = threadIdx.x & 31;
  const int ty = threadIdx.x >> 5;  // 0..7
  const int r0 = blockIdx.y * 32, c0 = blockIdx.x * 32;
#pragma unroll
  for (int j = 0; j < 32; j += 8)
    t[ty + j][tx] = (bf16)in[(long)(r0 + ty + j) * D_ + (c0 + tx)];
  __syncthreads();
#pragma unroll
  for (int j = 0; j < 32; j += 8)
    out[(long)(c0 + ty + j) * D_ + (r0 + tx)] = t[tx][ty + j];
}

// ---------------------------------------------------------------------------
// V [B,S,H,HD] (bf16) -> VT [B,H,HD,S]  (coalesced LDS-bounce transpose)
// ---------------------------------------------------------------------------
__global__ __launch_bounds__(256) void transpose_v64(const bf16* __restrict__ V,
                                                     bf16* __restrict__ VT) {
  __shared__ bf16 t[64][72];
  const int tid = threadIdx.x;
  const int s0 = blockIdx.x * 64;
  const int bh = blockIdx.y;
  const int b = bh >> 4, h = bh & 15;
  const bf16* ip = V + (long)b * S_ * D_ + h * HD_;
  bf16* op = VT + (long)bh * HD_ * S_;
#pragma unroll
  for (int i = 0; i < 2; ++i) {
    int c = tid + i * 256;
    int r = c >> 3, cc = (c & 7) * 8;
    *(bf16x8*)&t[r][cc] = *(const bf16x8*)&ip[(long)(s0 + r) * D_ + cc];
  }
  __syncthreads();
#pragma unroll
  for (int i = 0; i < 2; ++i) {
    int c = tid + i * 256;
    int d = c >> 3, sc = (c & 7) * 8;
    bf16x8 v;
#pragma unroll
    for (int j = 0; j < 8; ++j) v[j] = t[sc + j][d];
    *(bf16x8*)&op[(long)d * S_ + s0 + sc] = v;
  }
}

// ---------------------------------------------------------------------------
// Batched C[M,N] = A[M,K] @ Bt[N,K]^T + bias[N], z selects operand triple.
// BK=64 via two [128][32] half-buffers (keeps 64B-stride conflict-free
// fragment reads and DMA lane-contiguity); halves barrier count vs R12.
// R16: XCD-aware swizzle (XCD = dispatch_id % 8, id = bx + 8*by per z-plane):
// each XCD gets 4 contiguous bm-panels x all bn -> A 1MB + B 2MB L2-resident.
// ---------------------------------------------------------------------------
template <typename AT, typename OT>
__global__ __launch_bounds__(256) void gemm_bt_dma(
    const AT* __restrict__ A0, const AT* __restrict__ A1, const AT* __restrict__ A2,
    const bf16* __restrict__ B0, const bf16* __restrict__ B1, const bf16* __restrict__ B2,
    const float* __restrict__ c0, const float* __restrict__ c1, const float* __restrict__ c2,
    OT* __restrict__ C0, OT* __restrict__ C1, OT* __restrict__ C2,
    int M, int N, int K) {
  __shared__ bf16 lA[2][128][32];
  __shared__ bf16 lB[2][128][32];
  const int z = blockIdx.z;
  const AT*    A    = z == 0 ? A0 : z == 1 ? A1 : A2;
  const bf16*  Bt   = z == 0 ? B0 : z == 1 ? B1 : B2;
  const float* bias = z == 0 ? c0 : z == 1 ? c1 : c2;
  OT*          C    = z == 0 ? C0 : z == 1 ? C1 : C2;

  const int tid = threadIdx.x;
  const int lane = tid & 63, wave = tid >> 6;
  const int quad = lane >> 4, l16 = lane & 15;
  // bijective XCD swizzle within the 256-block z-plane (256 % 8 == 0)
  const int id = blockIdx.x + (blockIdx.y << 3);
  const int nid = (id & 7) * 32 + (id >> 3);
  const int bm = (nid >> 3) * 128, bn = (nid & 7) * 128;
  const int wm = (wave >> 1) * 64, wn = (wave & 1) * 64;

  f32x4 acc[4][4] = {};

  for (int k0 = 0; k0 < K; k0 += 64) {
    __syncthreads();
#pragma unroll
    for (int hh = 0; hh < 2; ++hh) {
#pragma unroll
      for (int i = 0; i < 2; ++i) {
        const int nbase = wave * 128 + i * 64;       // wave-uniform
        const int n = nbase + lane;                  // per-lane chunk
        const int row = n >> 2, kc = (n & 3) * 8;
        gld16(&lB[hh][0][0] + (long)nbase * 8,
              &Bt[(long)(bn + row) * K + k0 + hh * 32 + kc]);
        if constexpr (__is_same(AT, bf16))
          gld16(&lA[hh][0][0] + (long)nbase * 8,
                &A[(long)(bm + row) * K + k0 + hh * 32 + kc]);
      }
      if constexpr (!__is_same(AT, bf16)) {
#pragma unroll
        for (int i = 0; i < 2; ++i) {
          int c = tid + i * 256;
          int row = c >> 2, kc = (c & 3) * 8;
          *(bf16x8*)&lA[hh][row][kc] =
              load8(&A[(long)(bm + row) * K + k0 + hh * 32 + kc]);
        }
      }
    }
    __syncthreads();  // compiler drains vmcnt+lgkmcnt here
#pragma unroll
    for (int hh = 0; hh < 2; ++hh) {
      bf16x8 af[4], bfr[4];
#pragma unroll
      for (int i = 0; i < 4; ++i) {
        af[i]  = *(const bf16x8*)&lA[hh][wm + i * 16 + l16][quad * 8];
        bfr[i] = *(const bf16x8*)&lB[hh][wn + i * 16 + l16][quad * 8];
      }
#pragma unroll
      for (int mi = 0; mi < 4; ++mi)
#pragma unroll
        for (int ni = 0; ni < 4; ++ni)
          acc[mi][ni] = __builtin_amdgcn_mfma_f32_16x16x32_bf16(
              af[mi], bfr[ni], acc[mi][ni], 0, 0, 0);
    }
  }

  // epilogue: C/D layout col=lane&15, row=quad*4+reg (m89-verified)
#pragma unroll
  for (int mi = 0; mi < 4; ++mi)
#pragma unroll
    for (int ni = 0; ni < 4; ++ni) {
      int col = bn + wn + ni * 16 + l16;
      float bv = bias[col];
#pragma unroll
      for (int r = 0; r < 4; ++r) {
        int row = bm + wm + mi * 16 + quad * 4 + r;
        C[(long)row * N + col] = (OT)(acc[mi][ni][r] + bv);
      }
    }
}

// ---------------------------------------------------------------------------
// Final GEMM: 128x64 tiles (512 blocks = 2/CU), BK=64 half-buffer staging.
// R16: XCD swizzle (512 % 8 == 0): each XCD gets 4 bm-panels x all 16 bn
// -> A 1MB + B (WoT) 2MB L2-resident.
// ---------------------------------------------------------------------------
__global__ __launch_bounds__(256) void gemm_bt_64(const bf16* __restrict__ A,
                                                  const bf16* __restrict__ Bt,
                                                  const float* __restrict__ bias,
                                                  float* __restrict__ C,
                                                  int M, int N, int K) {
  __shared__ bf16 lA[2][128][32];
  __shared__ bf16 lB[2][64][32];
  const int tid = threadIdx.x;
  const int lane = tid & 63, wave = tid >> 6;
  const int quad = lane >> 4, l16 = lane & 15;
  const int id = blockIdx.x + (blockIdx.y << 4);
  const int nid = (id & 7) * 64 + (id >> 3);
  const int bm = (nid >> 4) * 128, bn = (nid & 15) * 64;
  const int wm = (wave >> 1) * 64, wn = (wave & 1) * 32;

  f32x4 acc[4][2] = {};

  for (int k0 = 0; k0 < K; k0 += 64) {
    __syncthreads();
#pragma unroll
    for (int hh = 0; hh < 2; ++hh) {
#pragma unroll
      for (int i = 0; i < 2; ++i) {
        const int nbase = wave * 128 + i * 64;
        const int n = nbase + lane;
        const int row = n >> 2, kc = (n & 3) * 8;
        gld16(&lA[hh][0][0] + (long)nbase * 8,
              &A[(long)(bm + row) * K + k0 + hh * 32 + kc]);
      }
      {
        const int nbase = wave * 64;
        const int n = nbase + lane;
        const int row = n >> 2, kc = (n & 3) * 8;
        gld16(&lB[hh][0][0] + (long)nbase * 8,
              &Bt[(long)(bn + row) * K + k0 + hh * 32 + kc]);
      }
    }
    __syncthreads();
#pragma unroll
    for (int hh = 0; hh < 2; ++hh) {
      bf16x8 af[4], bfr[2];
#pragma unroll
      for (int i = 0; i < 4; ++i)
        af[i] = *(const bf16x8*)&lA[hh][wm + i * 16 + l16][quad * 8];
#pragma unroll
      for (int i = 0; i < 2; ++i)
        bfr[i] = *(const bf16x8*)&lB[hh][wn + i * 16 + l16][quad * 8];
#pragma unroll
      for (int mi = 0; mi < 4; ++mi)
#pragma unroll
        for (int ni = 0; ni < 2; ++ni)
          acc[mi][ni] = __builtin_amdgcn_mfma_f32_16x16x32_bf16(
              af[mi], bfr[ni], acc[mi][ni], 0, 0, 0);
    }
  }

#pragma unroll
  for (int mi = 0; mi < 4; ++mi)
#pragma unroll
    for (int ni = 0; ni < 2; ++ni) {
      int col = bn + wn + ni * 16 + l16;
      float bv = bias[col];
#pragma unroll
      for (int r = 0; r < 4; ++r) {
        int row = bm + wm + mi * 16 + quad * 4 + r;
        C[(long)row * N + col] = acc[mi][ni][r] + bv;
      }
    }
}

// ---------------------------------------------------------------------------
// Flash attention v8 = v7 with PREFETCH DISTANCE 2.
// R2 post-mortem: v7's -30% aggregate work changed wall time by ~0 => wall is
// the longest block's chain: 32 iters x L (~3500 cyc). L is dominated by the
// vmcnt wait on K/V loads issued at the TOP of the same iteration (~900 cyc
// HBM latency >> the ~600 cyc of MFMA+softmax that could hide it).
// v8 holds two register tile-sets: while computing tile kt it issues loads
// for tile kt+2 and commits tile kt+1's regs (issued one full iteration +
// barrier ago -> vmcnt wait ~0). Explicit 2-step body (static reg naming);
// ktMax = qtB is always odd so no tail. +16 VGPR (40 -> ~56), no occupancy
// impact. Everything else byte-identical to v7.
// ---------------------------------------------------------------------------
#define SCALE_LOG2E 0.1803368801111244f  // (1/8) * log2(e)

__device__ inline void attn_step5(bool diag, int qloc, int quad, int l16,
                                  const bf16 (*lKb)[64], const bf16 (*lVb)[64],
                                  bf16 (*lpw)[72], const bf16x8* aq,
                                  f32x4* o, float& l_s) {
  const int sw = l16 & 7;
  f32x4 s[4];
#pragma unroll
  for (int ni = 0; ni < 4; ++ni) {
    f32x4 a = {};
#pragma unroll
    for (int c = 0; c < 2; ++c) {
      bf16x8 kf = *(const bf16x8*)&lKb[ni * 16 + l16][((c * 4 + quad) ^ sw) * 8];
      a = __builtin_amdgcn_mfma_f32_16x16x32_bf16(kf, aq[c], a, 0, 0, 0);
    }
    s[ni] = a * SCALE_LOG2E;
  }
  if (diag) {
#pragma unroll
    for (int ni = 0; ni < 4; ++ni)
#pragma unroll
      for (int r = 0; r < 4; ++r)
        if (ni * 16 + quad * 4 + r > qloc) s[ni][r] = -1e9f;  // exp2 -> 0
  }
  float rs = 0.f;
#pragma unroll
  for (int ni = 0; ni < 4; ++ni) {
    bf16x4 p4;
#pragma unroll
    for (int r = 0; r < 4; ++r) {
      float p = exp2g(s[ni][r]);
      p4[r] = (bf16)p;
      rs += p;
    }
    *(bf16x4*)&lpw[l16][ni * 16 + quad * 4] = p4;  // P[q][key], packed b64
  }
  l_s += rs;
#pragma unroll
  for (int c = 0; c < 2; ++c) {
    bf16x8 ap = *(const bf16x8*)&lpw[l16][c * 32 + quad * 8];
#pragma unroll
    for (int di = 0; di < 4; ++di) {
      bf16x8 vf = *(const bf16x8*)&lVb[di * 16 + l16][((c * 4 + quad) ^ sw) * 8];
      o[di] = __builtin_amdgcn_mfma_f32_16x16x32_bf16(vf, ap, o[di], 0, 0, 0);
    }
  }
}

__device__ inline void store_o(bf16* Ob, int qrow, int lane, int quad, int l16,
                               bf16 (*lpw)[72], const f32x4* o, float l_s) {
  float rs = l_s;
  rs += __shfl_xor(rs, 16);
  rs += __shfl_xor(rs, 32);
  const float inv = 1.0f / rs;
#pragma unroll
  for (int di = 0; di < 4; ++di) {
    bf16x4 p4;
#pragma unroll
    for (int r = 0; r < 4; ++r) p4[r] = (bf16)(o[di][r] * inv);
    *(bf16x4*)&lpw[l16][di * 16 + quad * 4] = p4;
  }
  const int q = lane >> 2, db = (lane & 3) * 16;
  bf16x8 v0 = *(const bf16x8*)&lpw[q][db];
  bf16x8 v1 = *(const bf16x8*)&lpw[q][db + 8];
  *(bf16x8*)&Ob[(long)(qrow + q) * D_ + db] = v0;
  *(bf16x8*)&Ob[(long)(qrow + q) * D_ + db + 8] = v1;
}

__global__ __launch_bounds__(512) void flash_attn8(const bf16* __restrict__ Q,
                                                   const bf16* __restrict__ K,
                                                   const bf16* __restrict__ VT,
                                                   bf16* __restrict__ O) {
  __shared__ bf16 lK[2][64][64];   // [key][dim], chunk-col XOR-swizzled
  __shared__ bf16 lV[2][64][64];   // [dim][key], chunk-col XOR-swizzled
  __shared__ bf16 lp[8][16][72];   // per-wave P / O bounce
  const int tid = threadIdx.x;
  const int lane = tid & 63, wave = tid >> 6;  // 0..7
  const int quad = lane >> 4, l16 = lane & 15;
  const int x = blockIdx.x, bh = blockIdx.y;
  // adjacent pairing; reversed in the upper bh half for per-CU load balance
  const bool flip = (bh & 16) != 0;
  const int qtA = flip ? 30 - 2 * x : 2 * x;
  const int qtB = qtA + 1;
  const bool isB = wave >= 4;
  const int w4 = wave & 3;
  const int myqt = isB ? qtB : qtA;
  const int b = bh >> 4, h = bh & 15;
  const bf16* Qb = Q + (long)b * S_ * D_ + h * HD_;
  const bf16* Kb = K + (long)b * S_ * D_ + h * HD_;
  const bf16* Vb = VT + (long)bh * HD_ * S_;
  const int qrow = myqt * 64 + w4 * 16;
  const int qloc = w4 * 16 + l16;

  bf16x8 aq[2];
#pragma unroll
  for (int c = 0; c < 2; ++c)
    aq[c] = *(const bf16x8*)&Qb[(long)(qrow + l16) * D_ + c * 32 + quad * 8];

  f32x4 o[4] = {};
  float l_s = 0.f;

  const int srow = tid >> 3, scol = tid & 7;
  const int swcol = (scol ^ (srow & 7)) * 8;
  const int ktMax = qtB;  // always odd

  // prologue: stage tile 0 into buf0; issue tile 1 (in flight across barrier)
  bf16x8 rkA, rvA, rkB, rvB;
  rkA = *(const bf16x8*)&Kb[(long)srow * D_ + scol * 8];
  rvA = *(const bf16x8*)&Vb[(long)srow * S_ + scol * 8];
  *(bf16x8*)&lK[0][srow][swcol] = rkA;
  *(bf16x8*)&lV[0][srow][swcol] = rvA;
  rkA = *(const bf16x8*)&Kb[(long)(64 + srow) * D_ + scol * 8];
  rvA = *(const bf16x8*)&Vb[(long)srow * S_ + 64 + scol * 8];
  __syncthreads();

  for (int kt = 0; kt < ktMax; kt += 2) {
    // ---- even step: compute tile kt on buf0; commit rA (tile kt+1) -> buf1
    if (kt + 2 <= ktMax) {  // issue tile kt+2 -> rB (consumed next even step)
      const long k0 = (long)(kt + 2) * 64;
      rkB = *(const bf16x8*)&Kb[(k0 + srow) * D_ + scol * 8];
      rvB = *(const bf16x8*)&Vb[(long)srow * S_ + k0 + scol * 8];
    }
    if (isB || kt <= qtA)
      attn_step5(kt == myqt, qloc, quad, l16, lK[0], lV[0], lp[wave], aq,
                 o, l_s);
    *(bf16x8*)&lK[1][srow][swcol] = rkA;  // vmcnt wait ~0: issued 1 iter ago
    *(bf16x8*)&lV[1][srow][swcol] = rvA;
    __syncthreads();
    // ---- odd step: compute tile kt+1 on buf1; commit rB (tile kt+2) -> buf0
    if (kt + 3 <= ktMax) {  // issue tile kt+3 -> rA
      const long k0 = (long)(kt + 3) * 64;
      rkA = *(const bf16x8*)&Kb[(k0 + srow) * D_ + scol * 8];
      rvA = *(const bf16x8*)&Vb[(long)srow * S_ + k0 + scol * 8];
    }
    if (isB || kt + 1 <= qtA)
      attn_step5(kt + 1 == myqt, qloc, quad, l16, lK[1], lV[1], lp[wave], aq,
                 o, l_s);
    if (kt + 1 < ktMax) {
      *(bf16x8*)&lK[0][srow][swcol] = rkB;
      *(bf16x8*)&lV[0][srow][swcol] = rvB;
      __syncthreads();
    }
  }

  bf16* Ob = O + (long)b * S_ * D_ + h * HD_;
  store_o(Ob, qrow, lane, quad, l16, lp[wave], o, l_s);
}

// ---------------------------------------------------------------------------
extern "C" void kernel_launch(void* const* d_in, const int* in_sizes, int n_in,
                              void* d_out, int out_size, void* d_ws, size_t ws_size,
                              hipStream_t stream) {
  (void)in_sizes; (void)n_in; (void)out_size;
  const float* q_in = (const float*)d_in[0];
  const float* k_in = (const float*)d_in[1];
  const float* v_in = (const float*)d_in[2];
  const float* Wq   = (const float*)d_in[3];
  const float* bq   = (const float*)d_in[4];
  const float* Wk   = (const float*)d_in[5];
  const float* bk   = (const float*)d_in[6];
  const float* Wv   = (const float*)d_in[7];
  const float* bv   = (const float*)d_in[8];
  const float* Wo   = (const float*)d_in[9];
  const float* bo   = (const float*)d_in[10];
  float* out = (float*)d_out;  // reference output dtype is float32

  bf16* ws = (bf16*)d_ws;
  const size_t WSZ = (size_t)D_ * D_;       // 1M elements
  const size_t TSZ = (size_t)B_ * S_ * D_;  // 4M elements
  bf16* WqT = ws;
  bf16* WkT = WqT + WSZ;
  bf16* WvT = WkT + WSZ;
  bf16* WoT = WvT + WSZ;
  bf16* Qp  = WoT + WSZ;
  bf16* Kp  = Qp + TSZ;
  bf16* Vp  = Kp + TSZ;
  bf16* VTp = Vp + TSZ;
  bf16* Ap  = VTp + TSZ;   // 48 MB used through here (validated R2-R14)
  // converted inputs: lifetimes end before VTp/Ap are written -> overlap
  bf16* Xq  = VTp;
  bf16* Xk  = Ap;
  bf16* Xv  = Ap + TSZ;    // needs ws_size >= 56 MB (validated R8-R14)
  const bool pre = ws_size >= (4 * WSZ + 6 * TSZ) * sizeof(bf16);

  dim3 blk(256);
  transpose_w<<<dim3(32, 32, pre ? 16 : 4), blk, 0, stream>>>(
      Wq, Wk, Wv, Wo, WqT, WkT, WvT, WoT, q_in, k_in, v_in, Xq, Xk, Xv);

  if (pre)
    gemm_bt_dma<bf16, bf16><<<dim3(8, 32, 3), blk, 0, stream>>>(
        Xq, Xk, Xv, WqT, WkT, WvT, bq, bk, bv, Qp, Kp, Vp, MM, D_, D_);
  else
    gemm_bt_dma<float, bf16><<<dim3(8, 32, 3), blk, 0, stream>>>(
        q_in, k_in, v_in, WqT, WkT, WvT, bq, bk, bv, Qp, Kp, Vp, MM, D_, D_);

  transpose_v64<<<dim3(S_ / 64, B_ * H_), blk, 0, stream>>>(Vp, VTp);

  flash_attn8<<<dim3(16, B_ * H_), dim3(512), 0, stream>>>(Qp, Kp, VTp, Ap);

  gemm_bt_64<<<dim3(16, 32), blk, 0, stream>>>(Ap, WoT, bo, out, MM, D_, D_);
}